// Round 4
// baseline (989.623 us; speedup 1.0000x reference)
//
#include <hip/hip_runtime.h>
#include <hip/hip_fp16.h>
#include <stdint.h>

#define VV 32000
#define HH 256
#define BB 32
#define TT 128
#define VH 32256  // V + H
#define NTILE 4000  // (4096/128) * (32000/256)

typedef _Float16 f16;
typedef _Float16 f16x2 __attribute__((ext_vector_type(2)));
typedef _Float16 f16x8 __attribute__((ext_vector_type(8)));
typedef float f32x4 __attribute__((ext_vector_type(4)));

static __device__ __forceinline__ float dot2f(uint32_t w, uint32_t h, float acc){
  f16x2 a = __builtin_bit_cast(f16x2, w);
  f16x2 b = __builtin_bit_cast(f16x2, h);
#if __has_builtin(__builtin_amdgcn_fdot2)
  return __builtin_amdgcn_fdot2(a, b, acc, false);
#else
  acc = fmaf((float)a[0], (float)b[0], acc);
  acc = fmaf((float)a[1], (float)b[1], acc);
  return acc;
#endif
}

// ---------------- control-block init (done[t] at ctl[t*16], arrival=ctl[2048], tiles=ctl[2049])
__global__ void k_init(int* __restrict__ ctl){
  int i = blockIdx.x*1024 + threadIdx.x;
  if (i < 2050) ctl[i] = 0;
}

// ---------------- gather: g[t*32+b][o] = W_gate[row][tok] + bias
__global__ void k_gather(const int* __restrict__ X,
                         const float* __restrict__ Wz, const float* __restrict__ bz,
                         const float* __restrict__ Wr, const float* __restrict__ br,
                         const float* __restrict__ Wh, const float* __restrict__ bh,
                         float* __restrict__ g_buf){
  int tb = blockIdx.x;              // t*32 + b
  int t = tb >> 5, b = tb & 31;
  int tok = X[b*TT + t];
  int o = threadIdx.x;              // 0..255
  g_buf[(size_t)tb*768 + o]       = Wz[(size_t)o*VH + tok] + bz[o];
  g_buf[(size_t)tb*768 + 256 + o] = Wr[(size_t)o*VH + tok] + br[o];
  g_buf[(size_t)tb*768 + 512 + o] = Wh[(size_t)o*VH + tok] + bh[o];
}

// ---------------- pack recurrent weights for 1024-thread recurrence layout
__global__ void k_pack(const float* __restrict__ Wz, const float* __restrict__ Wr,
                       const float* __restrict__ Wh, uint32_t* __restrict__ Wpack){
  int idx = blockIdx.x*256 + threadIdx.x;
  if (idx >= 1024*96) return;
  int t = idx / 96, rem = idx - t*96;
  int ol = rem >> 4, p = rem & 15;
  int ko = t & 7, no = t >> 3;
  int k = ko*32 + p*2;
  const float* W; int row;
  if (ol < 4){ int o = no*4 + ol; if (o < 256){ W = Wz; row = o; } else { W = Wr; row = o - 256; } }
  else { W = Wh; row = no*2 + (ol - 4); }
  float a = W[(size_t)row*VH + VV + k];
  float c = W[(size_t)row*VH + VV + k + 1];
  f16x2 v; v[0] = (f16)a; v[1] = (f16)c;
  Wpack[idx] = __builtin_bit_cast(uint32_t, v);
}

// ---------------- fused producer/consumer: 256 blocks x 1024 thr (1 block/CU)
// first 32 arrivals: recurrence (batch chain b). rest: t-gated GEMM tile consumers.
__global__ __launch_bounds__(1024) void k_fused(const float* __restrict__ H0,
    const uint32_t* __restrict__ Wpack, const float* __restrict__ g_buf,
    const float* __restrict__ Wo, const float* __restrict__ bo,
    f16* __restrict__ Hn16, float* __restrict__ Y, float* __restrict__ hf_out,
    int* __restrict__ ctl){
  __shared__ __align__(16) char smem[49152];
  __shared__ int sh_role;
  __shared__ int sh_tile;
  const int tid = threadIdx.x;
  if (tid == 0) sh_role = atomicAdd(&ctl[2048], 1);
  __syncthreads();
  const int role = sh_role;

  if (role < BB){
    // ================= producer: recurrence for batch b = role =================
    const int b = role;
    uint32_t* hs16 = (uint32_t*)smem;          // Hs as f16 pairs (512 B)
    f16*      rHs16 = (f16*)(smem + 512);      // r*Hs as f16 (512 B)
    float*    hs32 = (float*)(smem + 1024);    // Hs f32 (1 KiB)
    float*    z_s  = (float*)(smem + 2048);    // z gate (1 KiB)
    const int ko = tid & 7, no = tid >> 3;

    uint32_t w[6][16];
    {
      const uint4* src = (const uint4*)(Wpack + (size_t)tid*96);
      #pragma unroll
      for (int j=0;j<24;j++){
        uint4 v = src[j];
        int f = j*4;
        w[(f+0)>>4][(f+0)&15] = v.x;
        w[(f+1)>>4][(f+1)&15] = v.y;
        w[(f+2)>>4][(f+2)&15] = v.z;
        w[(f+3)>>4][(f+3)&15] = v.w;
      }
    }

    if (tid < 256) hs32[tid] = H0[b*HH + tid];
    __syncthreads();
    if (tid < 128){
      f16x2 v; v[0] = (f16)hs32[2*tid]; v[1] = (f16)hs32[2*tid+1];
      hs16[tid] = __builtin_bit_cast(uint32_t, v);
    }
    __syncthreads();

    const int gi1 = no*4 + ko;            // used when ko<4 (in-bounds junk otherwise)
    const int gi2 = 512 + no*2 + (ko & 1);
    float g1 = g_buf[(size_t)b*768 + gi1];
    float g2 = g_buf[(size_t)b*768 + gi2];
    float g1n = 0.f, g2n = 0.f;

    for (int t = 0; t < TT; t++){
      if (t < TT-1){
        const float* gn = g_buf + (size_t)((t+1)*BB + b)*768;
        g1n = gn[gi1];
        g2n = gn[gi2];
      }

      // ---- phase 1: z (no<64) and r (no>=64) pre-activations
      uint32_t hp[16];
      {
        const uint2* hsp = (const uint2*)hs16;
        #pragma unroll
        for (int j=0;j<8;j++){ uint2 v = hsp[ko*8 + j]; hp[2*j] = v.x; hp[2*j+1] = v.y; }
      }
      float acc[4];
      #pragma unroll
      for (int ol=0;ol<4;ol++) acc[ol] = 0.f;
      #pragma unroll
      for (int p=0;p<16;p++)
        #pragma unroll
        for (int ol=0;ol<4;ol++)
          acc[ol] = dot2f(w[ol][p], hp[p], acc[ol]);
      #pragma unroll
      for (int ol=0;ol<4;ol++){
        float v2 = acc[ol];
        v2 += __shfl_xor(v2, 1);
        v2 += __shfl_xor(v2, 2);
        v2 += __shfl_xor(v2, 4);
        acc[ol] = v2;
      }
      if (ko < 4){
        float pre = acc[ko] + g1;
        float s = 1.f / (1.f + __expf(-pre));
        int o = no*4 + ko;
        if (no < 64){
          z_s[o] = s;
        } else {
          int op = o - 256;
          rHs16[op] = (f16)(s * hs32[op]);
        }
      }
      __syncthreads();

      // ---- phase 2: h~ = tanh(gh + (r*Hs)@Wh^T), Hn = z*h~ + (1-z)*Hs
      uint32_t rp[16];
      {
        const uint2* rpp = (const uint2*)rHs16;
        #pragma unroll
        for (int j=0;j<8;j++){ uint2 v = rpp[ko*8 + j]; rp[2*j] = v.x; rp[2*j+1] = v.y; }
      }
      float a2[2];
      a2[0] = 0.f; a2[1] = 0.f;
      #pragma unroll
      for (int p=0;p<16;p++)
        #pragma unroll
        for (int oi=0;oi<2;oi++)
          a2[oi] = dot2f(w[4+oi][p], rp[p], a2[oi]);
      #pragma unroll
      for (int oi=0;oi<2;oi++){
        float v2 = a2[oi];
        v2 += __shfl_xor(v2, 1);
        v2 += __shfl_xor(v2, 2);
        v2 += __shfl_xor(v2, 4);
        a2[oi] = v2;
      }
      if (ko < 2){
        int o = no*2 + ko;
        float pre = a2[ko] + g2;
        float ax = fabsf(pre);
        float e = __expf(2.f*ax);
        float th = 1.f - 2.f/(e + 1.f);      // tanh(|x|), safe at inf
        th = copysignf(th, pre);
        float z = z_s[o];
        float hn = z*th + (1.f - z)*hs32[o];
        hs32[o] = hn;
        ((f16*)hs16)[o] = (f16)hn;
        Hn16[(size_t)(t*BB + b)*HH + o] = (f16)hn;
        if (t == TT-1) hf_out[b*HH + o] = hn;
      }
      g1 = g1n; g2 = g2n;
      __syncthreads();
      // release step t: all block stores drained to L2 by the barrier; wbl2 + device atomic
      if (tid == 0){ __threadfence(); atomicAdd(&ctl[t*16], 1); }
    }
  } else {
    // ================= consumer: Y tile [m0:m0+128) x [n0:n0+256) =================
    char* a_base = smem;            // [128][64] f16, XOR-swizzled (16 KiB)
    char* b_base = smem + 16384;    // [256][64] f16, XOR-swizzled (32 KiB)
    const int lane = tid & 63, wid = tid >> 6;
    const int wm = wid & 3, wn = wid >> 2;      // 4x4 waves: 32 rows x 64 cols each
    const int arow = tid >> 3, aseg = tid & 7;  // A-staging: 128 rows x 8 seg
    const int brow = tid >> 2, bq = tid & 3;    // B-staging: 256 rows x 4 q
    int fenced_t = -1;
    for (;;){
      if (tid == 0) sh_tile = atomicAdd(&ctl[2049], 1);
      __syncthreads();
      const int tile = sh_tile;
      if (tile >= NTILE) break;
      const int mg = tile / 125;
      const int ng = tile - mg*125;
      const int m0 = mg*128, n0 = ng*256;
      const int t_need = mg*4 + 3;
      if (tid == 0 && t_need > fenced_t){
        while (atomicAdd(&ctl[t_need*16], 0) < BB) __builtin_amdgcn_s_sleep(64);
        __threadfence();           // acquire: invalidate caches before reading Hn16
        fenced_t = t_need;
      }
      __syncthreads();

      f32x4 acc[2][4];
      {
        f32x4 z = {0.f,0.f,0.f,0.f};
        #pragma unroll
        for (int i=0;i<2;i++)
          #pragma unroll
          for (int j=0;j<4;j++) acc[i][j] = z;
      }

      #pragma unroll 1
      for (int kt=0; kt<4; kt++){
        {
          uint4 av = *(const uint4*)(Hn16 + (size_t)(m0+arow)*HH + kt*64 + aseg*8);
          *(uint4*)(a_base + ((arow*128 + aseg*16) ^ ((arow&7)<<4))) = av;
        }
        {
          const float4* bs = (const float4*)(Wo + (size_t)(n0+brow)*HH + kt*64 + bq*16);
          float4 f0=bs[0], f1=bs[1], f2=bs[2], f3=bs[3];
          f16x8 h0, h1;
          h0[0]=(f16)f0.x; h0[1]=(f16)f0.y; h0[2]=(f16)f0.z; h0[3]=(f16)f0.w;
          h0[4]=(f16)f1.x; h0[5]=(f16)f1.y; h0[6]=(f16)f1.z; h0[7]=(f16)f1.w;
          h1[0]=(f16)f2.x; h1[1]=(f16)f2.y; h1[2]=(f16)f2.z; h1[3]=(f16)f2.w;
          h1[4]=(f16)f3.x; h1[5]=(f16)f3.y; h1[6]=(f16)f3.z; h1[7]=(f16)f3.w;
          int base = brow*128 + bq*32;
          *(f16x8*)(b_base + ((base)    ^ ((brow&7)<<4))) = h0;
          *(f16x8*)(b_base + ((base+16) ^ ((brow&7)<<4))) = h1;
        }
        __syncthreads();
        #pragma unroll
        for (int kk=0; kk<2; kk++){
          const int kbyte = kk*64 + (lane>>4)*16;
          f16x8 af[2], bf[4];
          #pragma unroll
          for (int mi=0;mi<2;mi++){
            int row = wm*32 + mi*16 + (lane&15);
            af[mi] = *(const f16x8*)(a_base + ((row*128 + kbyte) ^ ((row&7)<<4)));
          }
          #pragma unroll
          for (int nj=0;nj<4;nj++){
            int rb = wn*64 + nj*16 + (lane&15);
            bf[nj] = *(const f16x8*)(b_base + ((rb*128 + kbyte) ^ ((rb&7)<<4)));
          }
          #pragma unroll
          for (int mi=0;mi<2;mi++)
            #pragma unroll
            for (int nj=0;nj<4;nj++)
              acc[mi][nj] = __builtin_amdgcn_mfma_f32_16x16x32_f16(af[mi], bf[nj], acc[mi][nj], 0, 0, 0);
        }
        __syncthreads();
      }
      // epilogue: C/D map: col = lane&15 (N), row = (lane>>4)*4 + reg (M)
      #pragma unroll
      for (int nj=0;nj<4;nj++){
        const int col = n0 + wn*64 + nj*16 + (lane & 15);
        const float bov = bo[col];
        #pragma unroll
        for (int mi=0;mi<2;mi++){
          const int rbase = m0 + wm*32 + mi*16 + (lane>>4)*4;
          #pragma unroll
          for (int r=0;r<4;r++)
            Y[(size_t)(rbase + r)*VV + col] = acc[mi][nj][r] + bov;
        }
      }
    }
  }
}

extern "C" void kernel_launch(void* const* d_in, const int* in_sizes, int n_in,
                              void* d_out, int out_size, void* d_ws, size_t ws_size,
                              hipStream_t stream){
  const int*   X  = (const int*)d_in[0];
  const float* H0 = (const float*)d_in[1];
  const float* Wz = (const float*)d_in[2];
  const float* bz = (const float*)d_in[3];
  const float* Wr = (const float*)d_in[4];
  const float* br = (const float*)d_in[5];
  const float* Wh = (const float*)d_in[6];
  const float* bh = (const float*)d_in[7];
  const float* Wo = (const float*)d_in[8];
  const float* bo = (const float*)d_in[9];
  float* out = (float*)d_out;

  char* ws = (char*)d_ws;
  float*    g_buf = (float*)ws;                               // 4096*768*4  = 12,582,912 B
  uint32_t* Wpack = (uint32_t*)(ws + 12582912);               // 1024*96*4   =    393,216 B
  f16*      Hn16  = (f16*)(ws + 12582912 + 393216);           // 4096*256*2  =  2,097,152 B
  int*      ctl   = (int*)(ws + 12582912 + 393216 + 2097152); // 2050*4      ≈      8,200 B

  k_init<<<3, 1024, 0, stream>>>(ctl);
  k_gather<<<4096, 256, 0, stream>>>(X, Wz, bz, Wr, br, Wh, bh, g_buf);
  k_pack<<<384, 256, 0, stream>>>(Wz, Wr, Wh, Wpack);
  k_fused<<<256, 1024, 0, stream>>>(H0, Wpack, g_buf, Wo, bo, Hn16, out, out + 131072000LL, ctl);
}

// Round 5
// 984.801 us; speedup vs baseline: 1.0049x; 1.0049x over previous
//
#include <hip/hip_runtime.h>
#include <hip/hip_fp16.h>
#include <stdint.h>

#define VV 32000
#define HH 256
#define BB 32
#define TT 128
#define VH 32256  // V + H
#define NTILE 4000  // (4096/128) * (32000/256)

typedef _Float16 f16;
typedef _Float16 f16x2 __attribute__((ext_vector_type(2)));
typedef _Float16 f16x8 __attribute__((ext_vector_type(8)));
typedef float f32x4 __attribute__((ext_vector_type(4)));

static __device__ __forceinline__ float dot2f(uint32_t w, uint32_t h, float acc){
  f16x2 a = __builtin_bit_cast(f16x2, w);
  f16x2 b = __builtin_bit_cast(f16x2, h);
#if __has_builtin(__builtin_amdgcn_fdot2)
  return __builtin_amdgcn_fdot2(a, b, acc, false);
#else
  acc = fmaf((float)a[0], (float)b[0], acc);
  acc = fmaf((float)a[1], (float)b[1], acc);
  return acc;
#endif
}

// ---------------- control-block init (done[t] at ctl[t*16], arrival=ctl[2048], tiles=ctl[2049])
__global__ void k_init(int* __restrict__ ctl){
  int i = blockIdx.x*1024 + threadIdx.x;
  if (i < 2050) ctl[i] = 0;
}

// ---------------- gather: g[t*32+b][o] = W_gate[row][tok] + bias
__global__ void k_gather(const int* __restrict__ X,
                         const float* __restrict__ Wz, const float* __restrict__ bz,
                         const float* __restrict__ Wr, const float* __restrict__ br,
                         const float* __restrict__ Wh, const float* __restrict__ bh,
                         float* __restrict__ g_buf){
  int tb = blockIdx.x;              // t*32 + b
  int t = tb >> 5, b = tb & 31;
  int tok = X[b*TT + t];
  int o = threadIdx.x;              // 0..255
  g_buf[(size_t)tb*768 + o]       = Wz[(size_t)o*VH + tok] + bz[o];
  g_buf[(size_t)tb*768 + 256 + o] = Wr[(size_t)o*VH + tok] + br[o];
  g_buf[(size_t)tb*768 + 512 + o] = Wh[(size_t)o*VH + tok] + bh[o];
}

// ---------------- pack recurrent weights for 1024-thread recurrence layout
__global__ void k_pack(const float* __restrict__ Wz, const float* __restrict__ Wr,
                       const float* __restrict__ Wh, uint32_t* __restrict__ Wpack){
  int idx = blockIdx.x*256 + threadIdx.x;
  if (idx >= 1024*96) return;
  int t = idx / 96, rem = idx - t*96;
  int ol = rem >> 4, p = rem & 15;
  int ko = t & 7, no = t >> 3;
  int k = ko*32 + p*2;
  const float* W; int row;
  if (ol < 4){ int o = no*4 + ol; if (o < 256){ W = Wz; row = o; } else { W = Wr; row = o - 256; } }
  else { W = Wh; row = no*2 + (ol - 4); }
  float a = W[(size_t)row*VH + VV + k];
  float c = W[(size_t)row*VH + VV + k + 1];
  f16x2 v; v[0] = (f16)a; v[1] = (f16)c;
  Wpack[idx] = __builtin_bit_cast(uint32_t, v);
}

// ---------------- fused producer/consumer: 256 blocks x 1024 thr, 1 block/CU
// __launch_bounds__(1024, 4): 4 waves/EU -> 128-VGPR cap -> producer weights stay in regs
__global__ __launch_bounds__(1024, 4) void k_fused(const float* __restrict__ H0,
    const uint32_t* __restrict__ Wpack, const float* __restrict__ g_buf,
    const float* __restrict__ Wo, const float* __restrict__ bo,
    f16* __restrict__ Hn16, float* __restrict__ Y, float* __restrict__ hf_out,
    int* __restrict__ ctl){
  __shared__ __align__(16) char smem[49152];
  __shared__ int sh_role;
  __shared__ int sh_tile;
  const int tid = threadIdx.x;
  if (tid == 0) sh_role = atomicAdd(&ctl[2048], 1);
  __syncthreads();
  const int role = sh_role;

  if (role < BB){
    // ================= producer: recurrence for batch b = role =================
    const int b = role;
    uint32_t* hs16 = (uint32_t*)smem;          // Hs as f16 pairs (512 B)
    f16*      rHs16 = (f16*)(smem + 512);      // r*Hs as f16 (512 B)
    float*    hs32 = (float*)(smem + 1024);    // Hs f32 (1 KiB)
    float*    z_s  = (float*)(smem + 2048);    // z gate (1 KiB)
    const int ko = tid & 7, no = tid >> 3;

    uint32_t w[6][16];
    {
      const uint4* src = (const uint4*)(Wpack + (size_t)tid*96);
      #pragma unroll
      for (int j=0;j<24;j++){
        uint4 v = src[j];
        int f = j*4;
        w[(f+0)>>4][(f+0)&15] = v.x;
        w[(f+1)>>4][(f+1)&15] = v.y;
        w[(f+2)>>4][(f+2)&15] = v.z;
        w[(f+3)>>4][(f+3)&15] = v.w;
      }
    }

    if (tid < 256) hs32[tid] = H0[b*HH + tid];
    __syncthreads();
    if (tid < 128){
      f16x2 v; v[0] = (f16)hs32[2*tid]; v[1] = (f16)hs32[2*tid+1];
      hs16[tid] = __builtin_bit_cast(uint32_t, v);
    }
    __syncthreads();

    const int gi1 = no*4 + ko;            // used when ko<4 (in-bounds junk otherwise)
    const int gi2 = 512 + no*2 + (ko & 1);
    float g1 = g_buf[(size_t)b*768 + gi1];
    float g2 = g_buf[(size_t)b*768 + gi2];
    float g1n = 0.f, g2n = 0.f;

    for (int t = 0; t < TT; t++){
      if (t < TT-1){
        const float* gn = g_buf + (size_t)((t+1)*BB + b)*768;
        g1n = gn[gi1];
        g2n = gn[gi2];
      }

      // ---- phase 1: z (no<64) and r (no>=64) pre-activations
      uint32_t hp[16];
      {
        const uint2* hsp = (const uint2*)hs16;
        #pragma unroll
        for (int j=0;j<8;j++){ uint2 v = hsp[ko*8 + j]; hp[2*j] = v.x; hp[2*j+1] = v.y; }
      }
      float acc[4];
      #pragma unroll
      for (int ol=0;ol<4;ol++) acc[ol] = 0.f;
      #pragma unroll
      for (int p=0;p<16;p++)
        #pragma unroll
        for (int ol=0;ol<4;ol++)
          acc[ol] = dot2f(w[ol][p], hp[p], acc[ol]);
      #pragma unroll
      for (int ol=0;ol<4;ol++){
        float v2 = acc[ol];
        v2 += __shfl_xor(v2, 1);
        v2 += __shfl_xor(v2, 2);
        v2 += __shfl_xor(v2, 4);
        acc[ol] = v2;
      }
      if (ko < 4){
        float pre = acc[ko] + g1;
        float s = 1.f / (1.f + __expf(-pre));
        int o = no*4 + ko;
        if (no < 64){
          z_s[o] = s;
        } else {
          int op = o - 256;
          rHs16[op] = (f16)(s * hs32[op]);
        }
      }
      __syncthreads();

      // ---- phase 2: h~ = tanh(gh + (r*Hs)@Wh^T), Hn = z*h~ + (1-z)*Hs
      uint32_t rp[16];
      {
        const uint2* rpp = (const uint2*)rHs16;
        #pragma unroll
        for (int j=0;j<8;j++){ uint2 v = rpp[ko*8 + j]; rp[2*j] = v.x; rp[2*j+1] = v.y; }
      }
      float a2[2];
      a2[0] = 0.f; a2[1] = 0.f;
      #pragma unroll
      for (int p=0;p<16;p++)
        #pragma unroll
        for (int oi=0;oi<2;oi++)
          a2[oi] = dot2f(w[4+oi][p], rp[p], a2[oi]);
      #pragma unroll
      for (int oi=0;oi<2;oi++){
        float v2 = a2[oi];
        v2 += __shfl_xor(v2, 1);
        v2 += __shfl_xor(v2, 2);
        v2 += __shfl_xor(v2, 4);
        a2[oi] = v2;
      }
      if (ko < 2){
        int o = no*2 + ko;
        float pre = a2[ko] + g2;
        float ax = fabsf(pre);
        float e = __expf(2.f*ax);
        float th = 1.f - 2.f/(e + 1.f);      // tanh(|x|), safe at inf
        th = copysignf(th, pre);
        float z = z_s[o];
        float hn = z*th + (1.f - z)*hs32[o];
        hs32[o] = hn;
        ((f16*)hs16)[o] = (f16)hn;
        Hn16[(size_t)(t*BB + b)*HH + o] = (f16)hn;
        if (t == TT-1) hf_out[b*HH + o] = hn;
      }
      g1 = g1n; g2 = g2n;
      __syncthreads();
      // release step t: all block stores drained by the barrier; device-scope publish
      if (tid == 0){ __threadfence(); atomicAdd(&ctl[t*16], 1); }
    }
  } else {
    // ================= consumer: Y tile [m0:m0+128) x [n0:n0+256) =================
    char* a_base = smem;            // [128][64] f16, XOR-swizzled (16 KiB)
    char* b_base = smem + 16384;    // [256][64] f16, XOR-swizzled (32 KiB)
    const int lane = tid & 63, wid = tid >> 6;
    const int wm = wid & 3, wn = wid >> 2;      // 4x4 waves: 32 rows x 64 cols each
    const int arow = tid >> 3, aseg = tid & 7;  // A-staging: 128 rows x 8 seg
    const int brow = tid >> 2, bq = tid & 3;    // B-staging: 256 rows x 4 q
    int fenced_t = -1;
    for (;;){
      if (tid == 0) sh_tile = atomicAdd(&ctl[2049], 1);
      __syncthreads();
      const int tile = sh_tile;
      if (tile >= NTILE) break;
      const int mg = tile / 125;
      const int ng = tile - mg*125;
      const int m0 = mg*128, n0 = ng*256;
      const int t_need = mg*4 + 3;
      if (tid == 0 && t_need > fenced_t){
        while (atomicAdd(&ctl[t_need*16], 0) < BB) __builtin_amdgcn_s_sleep(64);
        __threadfence();           // acquire before reading Hn16
        fenced_t = t_need;
      }
      __syncthreads();

      f32x4 acc[2][4];
      {
        f32x4 z = {0.f,0.f,0.f,0.f};
        #pragma unroll
        for (int i=0;i<2;i++)
          #pragma unroll
          for (int j=0;j<4;j++) acc[i][j] = z;
      }

      #pragma unroll 1
      for (int kt=0; kt<4; kt++){
        {
          uint4 av = *(const uint4*)(Hn16 + (size_t)(m0+arow)*HH + kt*64 + aseg*8);
          *(uint4*)(a_base + ((arow*128 + aseg*16) ^ ((arow&7)<<4))) = av;
        }
        {
          const float4* bs = (const float4*)(Wo + (size_t)(n0+brow)*HH + kt*64 + bq*16);
          float4 f0=bs[0], f1=bs[1], f2=bs[2], f3=bs[3];
          f16x8 h0, h1;
          h0[0]=(f16)f0.x; h0[1]=(f16)f0.y; h0[2]=(f16)f0.z; h0[3]=(f16)f0.w;
          h0[4]=(f16)f1.x; h0[5]=(f16)f1.y; h0[6]=(f16)f1.z; h0[7]=(f16)f1.w;
          h1[0]=(f16)f2.x; h1[1]=(f16)f2.y; h1[2]=(f16)f2.z; h1[3]=(f16)f2.w;
          h1[4]=(f16)f3.x; h1[5]=(f16)f3.y; h1[6]=(f16)f3.z; h1[7]=(f16)f3.w;
          int base = brow*128 + bq*32;
          *(f16x8*)(b_base + ((base)    ^ ((brow&7)<<4))) = h0;
          *(f16x8*)(b_base + ((base+16) ^ ((brow&7)<<4))) = h1;
        }
        __syncthreads();
        #pragma unroll
        for (int kk=0; kk<2; kk++){
          const int kbyte = kk*64 + (lane>>4)*16;
          f16x8 af[2], bf[4];
          #pragma unroll
          for (int mi=0;mi<2;mi++){
            int row = wm*32 + mi*16 + (lane&15);
            af[mi] = *(const f16x8*)(a_base + ((row*128 + kbyte) ^ ((row&7)<<4)));
          }
          #pragma unroll
          for (int nj=0;nj<4;nj++){
            int rb = wn*64 + nj*16 + (lane&15);
            bf[nj] = *(const f16x8*)(b_base + ((rb*128 + kbyte) ^ ((rb&7)<<4)));
          }
          #pragma unroll
          for (int mi=0;mi<2;mi++)
            #pragma unroll
            for (int nj=0;nj<4;nj++)
              acc[mi][nj] = __builtin_amdgcn_mfma_f32_16x16x32_f16(af[mi], bf[nj], acc[mi][nj], 0, 0, 0);
        }
        __syncthreads();
      }
      // epilogue: C/D map: col = lane&15 (N), row = (lane>>4)*4 + reg (M)
      #pragma unroll
      for (int nj=0;nj<4;nj++){
        const int col = n0 + wn*64 + nj*16 + (lane & 15);
        const float bov = bo[col];
        #pragma unroll
        for (int mi=0;mi<2;mi++){
          const int rbase = m0 + wm*32 + mi*16 + (lane>>4)*4;
          #pragma unroll
          for (int r=0;r<4;r++)
            Y[(size_t)(rbase + r)*VV + col] = acc[mi][nj][r] + bov;
        }
      }
    }
  }
}

extern "C" void kernel_launch(void* const* d_in, const int* in_sizes, int n_in,
                              void* d_out, int out_size, void* d_ws, size_t ws_size,
                              hipStream_t stream){
  const int*   X  = (const int*)d_in[0];
  const float* H0 = (const float*)d_in[1];
  const float* Wz = (const float*)d_in[2];
  const float* bz = (const float*)d_in[3];
  const float* Wr = (const float*)d_in[4];
  const float* br = (const float*)d_in[5];
  const float* Wh = (const float*)d_in[6];
  const float* bh = (const float*)d_in[7];
  const float* Wo = (const float*)d_in[8];
  const float* bo = (const float*)d_in[9];
  float* out = (float*)d_out;

  char* ws = (char*)d_ws;
  float*    g_buf = (float*)ws;                               // 4096*768*4  = 12,582,912 B
  uint32_t* Wpack = (uint32_t*)(ws + 12582912);               // 1024*96*4   =    393,216 B
  f16*      Hn16  = (f16*)(ws + 12582912 + 393216);           // 4096*256*2  =  2,097,152 B
  int*      ctl   = (int*)(ws + 12582912 + 393216 + 2097152); // 2050*4      ≈      8,200 B

  k_init<<<3, 1024, 0, stream>>>(ctl);
  k_gather<<<4096, 256, 0, stream>>>(X, Wz, bz, Wr, br, Wh, bh, g_buf);
  k_pack<<<384, 256, 0, stream>>>(Wz, Wr, Wh, Wpack);
  k_fused<<<256, 1024, 0, stream>>>(H0, Wpack, g_buf, Wo, bo, Hn16, out, out + 131072000LL, ctl);
}

// Round 6
// 980.087 us; speedup vs baseline: 1.0097x; 1.0048x over previous
//
#include <hip/hip_runtime.h>
#include <hip/hip_fp16.h>
#include <stdint.h>

#define VV 32000
#define HH 256
#define BB 32
#define TT 128
#define VH 32256  // V + H
#define NTILE 4000  // (4096/128) * (32000/256)

typedef _Float16 f16;
typedef _Float16 f16x2 __attribute__((ext_vector_type(2)));
typedef _Float16 f16x8 __attribute__((ext_vector_type(8)));
typedef float f32x4 __attribute__((ext_vector_type(4)));

static __device__ __forceinline__ float dot2f(uint32_t w, uint32_t h, float acc){
  f16x2 a = __builtin_bit_cast(f16x2, w);
  f16x2 b = __builtin_bit_cast(f16x2, h);
#if __has_builtin(__builtin_amdgcn_fdot2)
  return __builtin_amdgcn_fdot2(a, b, acc, false);
#else
  acc = fmaf((float)a[0], (float)b[0], acc);
  acc = fmaf((float)a[1], (float)b[1], acc);
  return acc;
#endif
}

// ---------------- control-block init (done[t] at ctl[t*16], arrival=ctl[2048], tiles=ctl[2049])
__global__ void k_init(int* __restrict__ ctl){
  int i = blockIdx.x*1024 + threadIdx.x;
  if (i < 2050) ctl[i] = 0;
}

// ---------------- gather: g[t*32+b][o] = W_gate[row][tok] + bias
__global__ void k_gather(const int* __restrict__ X,
                         const float* __restrict__ Wz, const float* __restrict__ bz,
                         const float* __restrict__ Wr, const float* __restrict__ br,
                         const float* __restrict__ Wh, const float* __restrict__ bh,
                         float* __restrict__ g_buf){
  int tb = blockIdx.x;              // t*32 + b
  int t = tb >> 5, b = tb & 31;
  int tok = X[b*TT + t];
  int o = threadIdx.x;              // 0..255
  g_buf[(size_t)tb*768 + o]       = Wz[(size_t)o*VH + tok] + bz[o];
  g_buf[(size_t)tb*768 + 256 + o] = Wr[(size_t)o*VH + tok] + br[o];
  g_buf[(size_t)tb*768 + 512 + o] = Wh[(size_t)o*VH + tok] + bh[o];
}

// ---------------- pack recurrent weights for 1024-thread recurrence layout
__global__ void k_pack(const float* __restrict__ Wz, const float* __restrict__ Wr,
                       const float* __restrict__ Wh, uint32_t* __restrict__ Wpack){
  int idx = blockIdx.x*256 + threadIdx.x;
  if (idx >= 1024*96) return;
  int t = idx / 96, rem = idx - t*96;
  int ol = rem >> 4, p = rem & 15;
  int ko = t & 7, no = t >> 3;
  int k = ko*32 + p*2;
  const float* W; int row;
  if (ol < 4){ int o = no*4 + ol; if (o < 256){ W = Wz; row = o; } else { W = Wr; row = o - 256; } }
  else { W = Wh; row = no*2 + (ol - 4); }
  float a = W[(size_t)row*VH + VV + k];
  float c = W[(size_t)row*VH + VV + k + 1];
  f16x2 v; v[0] = (f16)a; v[1] = (f16)c;
  Wpack[idx] = __builtin_bit_cast(uint32_t, v);
}

// ---------------- fused producer/consumer: 256 blocks x 1024 thr, 1 block/CU
// __launch_bounds__(1024, 1): min-blocks semantics -> 1 block/CU -> 128-VGPR cap,
// producer weight array stays in registers (no scratch spill).
__global__ __launch_bounds__(1024, 1) void k_fused(const float* __restrict__ H0,
    const uint32_t* __restrict__ Wpack, const float* __restrict__ g_buf,
    const float* __restrict__ Wo, const float* __restrict__ bo,
    f16* __restrict__ Hn16, float* __restrict__ Y, float* __restrict__ hf_out,
    int* __restrict__ ctl){
  __shared__ __align__(16) char smem[49152];
  __shared__ int sh_role;
  __shared__ int sh_tile;
  const int tid = threadIdx.x;
  if (tid == 0) sh_role = atomicAdd(&ctl[2048], 1);
  __syncthreads();
  const int role = sh_role;

  if (role < BB){
    // ================= producer: recurrence for batch b = role =================
    const int b = role;
    uint32_t* hs16 = (uint32_t*)smem;          // Hs as f16 pairs (512 B)
    f16*      rHs16 = (f16*)(smem + 512);      // r*Hs as f16 (512 B)
    float*    hs32 = (float*)(smem + 1024);    // Hs f32 (1 KiB)
    float*    z_s  = (float*)(smem + 2048);    // z gate (1 KiB)
    const int ko = tid & 7, no = tid >> 3;

    uint32_t w[6][16];
    {
      const uint4* src = (const uint4*)(Wpack + (size_t)tid*96);
      #pragma unroll
      for (int j=0;j<24;j++){
        uint4 v = src[j];
        int f = j*4;
        w[(f+0)>>4][(f+0)&15] = v.x;
        w[(f+1)>>4][(f+1)&15] = v.y;
        w[(f+2)>>4][(f+2)&15] = v.z;
        w[(f+3)>>4][(f+3)&15] = v.w;
      }
    }

    if (tid < 256) hs32[tid] = H0[b*HH + tid];
    __syncthreads();
    if (tid < 128){
      f16x2 v; v[0] = (f16)hs32[2*tid]; v[1] = (f16)hs32[2*tid+1];
      hs16[tid] = __builtin_bit_cast(uint32_t, v);
    }
    __syncthreads();

    const int gi1 = no*4 + ko;            // used when ko<4 (in-bounds junk otherwise)
    const int gi2 = 512 + no*2 + (ko & 1);
    float g1 = g_buf[(size_t)b*768 + gi1];
    float g2 = g_buf[(size_t)b*768 + gi2];
    float g1n = 0.f, g2n = 0.f;

    for (int t = 0; t < TT; t++){
      if (t < TT-1){
        const float* gn = g_buf + (size_t)((t+1)*BB + b)*768;
        g1n = gn[gi1];
        g2n = gn[gi2];
      }

      // ---- phase 1: z (no<64) and r (no>=64) pre-activations
      uint32_t hp[16];
      {
        const uint2* hsp = (const uint2*)hs16;
        #pragma unroll
        for (int j=0;j<8;j++){ uint2 v = hsp[ko*8 + j]; hp[2*j] = v.x; hp[2*j+1] = v.y; }
      }
      float acc[4];
      #pragma unroll
      for (int ol=0;ol<4;ol++) acc[ol] = 0.f;
      #pragma unroll
      for (int p=0;p<16;p++)
        #pragma unroll
        for (int ol=0;ol<4;ol++)
          acc[ol] = dot2f(w[ol][p], hp[p], acc[ol]);
      #pragma unroll
      for (int ol=0;ol<4;ol++){
        float v2 = acc[ol];
        v2 += __shfl_xor(v2, 1);
        v2 += __shfl_xor(v2, 2);
        v2 += __shfl_xor(v2, 4);
        acc[ol] = v2;
      }
      if (ko < 4){
        float pre = acc[ko] + g1;
        float s = 1.f / (1.f + __expf(-pre));
        int o = no*4 + ko;
        if (no < 64){
          z_s[o] = s;
        } else {
          int op = o - 256;
          rHs16[op] = (f16)(s * hs32[op]);
        }
      }
      __syncthreads();

      // ---- phase 2: h~ = tanh(gh + (r*Hs)@Wh^T), Hn = z*h~ + (1-z)*Hs
      uint32_t rp[16];
      {
        const uint2* rpp = (const uint2*)rHs16;
        #pragma unroll
        for (int j=0;j<8;j++){ uint2 v = rpp[ko*8 + j]; rp[2*j] = v.x; rp[2*j+1] = v.y; }
      }
      float a2[2];
      a2[0] = 0.f; a2[1] = 0.f;
      #pragma unroll
      for (int p=0;p<16;p++)
        #pragma unroll
        for (int oi=0;oi<2;oi++)
          a2[oi] = dot2f(w[4+oi][p], rp[p], a2[oi]);
      #pragma unroll
      for (int oi=0;oi<2;oi++){
        float v2 = a2[oi];
        v2 += __shfl_xor(v2, 1);
        v2 += __shfl_xor(v2, 2);
        v2 += __shfl_xor(v2, 4);
        a2[oi] = v2;
      }
      if (ko < 2){
        int o = no*2 + ko;
        float pre = a2[ko] + g2;
        float ax = fabsf(pre);
        float e = __expf(2.f*ax);
        float th = 1.f - 2.f/(e + 1.f);      // tanh(|x|), safe at inf
        th = copysignf(th, pre);
        float z = z_s[o];
        float hn = z*th + (1.f - z)*hs32[o];
        hs32[o] = hn;
        ((f16*)hs16)[o] = (f16)hn;
        Hn16[(size_t)(t*BB + b)*HH + o] = (f16)hn;
        if (t == TT-1) hf_out[b*HH + o] = hn;
      }
      g1 = g1n; g2 = g2n;
      __syncthreads();
      // release step t: all block stores drained by the barrier; device-scope publish
      if (tid == 0){ __threadfence(); atomicAdd(&ctl[t*16], 1); }
    }
  } else {
    // ================= consumer: Y tile [m0:m0+128) x [n0:n0+256) =================
    char* a_base = smem;            // [128][64] f16, XOR-swizzled (16 KiB)
    char* b_base = smem + 16384;    // [256][64] f16, XOR-swizzled (32 KiB)
    const int lane = tid & 63, wid = tid >> 6;
    const int wm = wid & 3, wn = wid >> 2;      // 4x4 waves: 32 rows x 64 cols each
    const int arow = tid >> 3, aseg = tid & 7;  // A-staging: 128 rows x 8 seg
    const int brow = tid >> 2, bq = tid & 3;    // B-staging: 256 rows x 4 q
    int fenced_t = -1;
    for (;;){
      if (tid == 0) sh_tile = atomicAdd(&ctl[2049], 1);
      __syncthreads();
      const int tile = sh_tile;
      if (tile >= NTILE) break;
      const int mg = tile / 125;
      const int ng = tile - mg*125;
      const int m0 = mg*128, n0 = ng*256;
      const int t_need = mg*4 + 3;
      if (tid == 0 && t_need > fenced_t){
        while (atomicAdd(&ctl[t_need*16], 0) < BB) __builtin_amdgcn_s_sleep(64);
        __threadfence();           // acquire before reading Hn16
        fenced_t = t_need;
      }
      __syncthreads();

      f32x4 acc[2][4];
      {
        f32x4 z = {0.f,0.f,0.f,0.f};
        #pragma unroll
        for (int i=0;i<2;i++)
          #pragma unroll
          for (int j=0;j<4;j++) acc[i][j] = z;
      }

      #pragma unroll 1
      for (int kt=0; kt<4; kt++){
        {
          uint4 av = *(const uint4*)(Hn16 + (size_t)(m0+arow)*HH + kt*64 + aseg*8);
          *(uint4*)(a_base + ((arow*128 + aseg*16) ^ ((arow&7)<<4))) = av;
        }
        {
          const float4* bs = (const float4*)(Wo + (size_t)(n0+brow)*HH + kt*64 + bq*16);
          float4 f0=bs[0], f1=bs[1], f2=bs[2], f3=bs[3];
          f16x8 h0, h1;
          h0[0]=(f16)f0.x; h0[1]=(f16)f0.y; h0[2]=(f16)f0.z; h0[3]=(f16)f0.w;
          h0[4]=(f16)f1.x; h0[5]=(f16)f1.y; h0[6]=(f16)f1.z; h0[7]=(f16)f1.w;
          h1[0]=(f16)f2.x; h1[1]=(f16)f2.y; h1[2]=(f16)f2.z; h1[3]=(f16)f2.w;
          h1[4]=(f16)f3.x; h1[5]=(f16)f3.y; h1[6]=(f16)f3.z; h1[7]=(f16)f3.w;
          int base = brow*128 + bq*32;
          *(f16x8*)(b_base + ((base)    ^ ((brow&7)<<4))) = h0;
          *(f16x8*)(b_base + ((base+16) ^ ((brow&7)<<4))) = h1;
        }
        __syncthreads();
        #pragma unroll
        for (int kk=0; kk<2; kk++){
          const int kbyte = kk*64 + (lane>>4)*16;
          f16x8 af[2], bf[4];
          #pragma unroll
          for (int mi=0;mi<2;mi++){
            int row = wm*32 + mi*16 + (lane&15);
            af[mi] = *(const f16x8*)(a_base + ((row*128 + kbyte) ^ ((row&7)<<4)));
          }
          #pragma unroll
          for (int nj=0;nj<4;nj++){
            int rb = wn*64 + nj*16 + (lane&15);
            bf[nj] = *(const f16x8*)(b_base + ((rb*128 + kbyte) ^ ((rb&7)<<4)));
          }
          #pragma unroll
          for (int mi=0;mi<2;mi++)
            #pragma unroll
            for (int nj=0;nj<4;nj++)
              acc[mi][nj] = __builtin_amdgcn_mfma_f32_16x16x32_f16(af[mi], bf[nj], acc[mi][nj], 0, 0, 0);
        }
        __syncthreads();
      }
      // epilogue: C/D map: col = lane&15 (N), row = (lane>>4)*4 + reg (M)
      #pragma unroll
      for (int nj=0;nj<4;nj++){
        const int col = n0 + wn*64 + nj*16 + (lane & 15);
        const float bov = bo[col];
        #pragma unroll
        for (int mi=0;mi<2;mi++){
          const int rbase = m0 + wm*32 + mi*16 + (lane>>4)*4;
          #pragma unroll
          for (int r=0;r<4;r++)
            Y[(size_t)(rbase + r)*VV + col] = acc[mi][nj][r] + bov;
        }
      }
    }
  }
}

extern "C" void kernel_launch(void* const* d_in, const int* in_sizes, int n_in,
                              void* d_out, int out_size, void* d_ws, size_t ws_size,
                              hipStream_t stream){
  const int*   X  = (const int*)d_in[0];
  const float* H0 = (const float*)d_in[1];
  const float* Wz = (const float*)d_in[2];
  const float* bz = (const float*)d_in[3];
  const float* Wr = (const float*)d_in[4];
  const float* br = (const float*)d_in[5];
  const float* Wh = (const float*)d_in[6];
  const float* bh = (const float*)d_in[7];
  const float* Wo = (const float*)d_in[8];
  const float* bo = (const float*)d_in[9];
  float* out = (float*)d_out;

  char* ws = (char*)d_ws;
  float*    g_buf = (float*)ws;                               // 4096*768*4  = 12,582,912 B
  uint32_t* Wpack = (uint32_t*)(ws + 12582912);               // 1024*96*4   =    393,216 B
  f16*      Hn16  = (f16*)(ws + 12582912 + 393216);           // 4096*256*2  =  2,097,152 B
  int*      ctl   = (int*)(ws + 12582912 + 393216 + 2097152); // 2050*4      ≈      8,200 B

  k_init<<<3, 1024, 0, stream>>>(ctl);
  k_gather<<<4096, 256, 0, stream>>>(X, Wz, bz, Wr, br, Wh, bh, g_buf);
  k_pack<<<384, 256, 0, stream>>>(Wz, Wr, Wh, Wpack);
  k_fused<<<256, 1024, 0, stream>>>(H0, Wpack, g_buf, Wo, bo, Hn16, out, out + 131072000LL, ctl);
}

// Round 7
// 957.399 us; speedup vs baseline: 1.0337x; 1.0237x over previous
//
#include <hip/hip_runtime.h>
#include <hip/hip_fp16.h>
#include <stdint.h>

#define VV 32000
#define HH 256
#define BB 32
#define TT 128
#define VH 32256  // V + H
#define NTILE 4000  // (4096/128) * (32000/256)

typedef _Float16 f16;
typedef _Float16 f16x2 __attribute__((ext_vector_type(2)));
typedef _Float16 f16x8 __attribute__((ext_vector_type(8)));
typedef float f32x4 __attribute__((ext_vector_type(4)));

static __device__ __forceinline__ float dot2f(uint32_t w, uint32_t h, float acc){
  f16x2 a = __builtin_bit_cast(f16x2, w);
  f16x2 b = __builtin_bit_cast(f16x2, h);
#if __has_builtin(__builtin_amdgcn_fdot2)
  return __builtin_amdgcn_fdot2(a, b, acc, false);
#else
  acc = fmaf((float)a[0], (float)b[0], acc);
  acc = fmaf((float)a[1], (float)b[1], acc);
  return acc;
#endif
}

// ---------------- control-block init (done[t] at ctl[t*16], arrival=ctl[2048], tiles=ctl[2049])
__global__ void k_init(int* __restrict__ ctl){
  int i = blockIdx.x*1024 + threadIdx.x;
  if (i < 2050) ctl[i] = 0;
}

// ---------------- gather: g[t*32+b][o] = W_gate[row][tok] + bias
__global__ void k_gather(const int* __restrict__ X,
                         const float* __restrict__ Wz, const float* __restrict__ bz,
                         const float* __restrict__ Wr, const float* __restrict__ br,
                         const float* __restrict__ Wh, const float* __restrict__ bh,
                         float* __restrict__ g_buf){
  int tb = blockIdx.x;              // t*32 + b
  int t = tb >> 5, b = tb & 31;
  int tok = X[b*TT + t];
  int o = threadIdx.x;              // 0..255
  g_buf[(size_t)tb*768 + o]       = Wz[(size_t)o*VH + tok] + bz[o];
  g_buf[(size_t)tb*768 + 256 + o] = Wr[(size_t)o*VH + tok] + br[o];
  g_buf[(size_t)tb*768 + 512 + o] = Wh[(size_t)o*VH + tok] + bh[o];
}

// ---------------- pack recurrent weights for 1024-thread recurrence layout
__global__ void k_pack(const float* __restrict__ Wz, const float* __restrict__ Wr,
                       const float* __restrict__ Wh, uint32_t* __restrict__ Wpack){
  int idx = blockIdx.x*256 + threadIdx.x;
  if (idx >= 1024*96) return;
  int t = idx / 96, rem = idx - t*96;
  int ol = rem >> 4, p = rem & 15;
  int ko = t & 7, no = t >> 3;
  int k = ko*32 + p*2;
  const float* W; int row;
  if (ol < 4){ int o = no*4 + ol; if (o < 256){ W = Wz; row = o; } else { W = Wr; row = o - 256; } }
  else { W = Wh; row = no*2 + (ol - 4); }
  float a = W[(size_t)row*VH + VV + k];
  float c = W[(size_t)row*VH + VV + k + 1];
  f16x2 v; v[0] = (f16)a; v[1] = (f16)c;
  Wpack[idx] = __builtin_bit_cast(uint32_t, v);
}

// ---------------- fused producer/consumer: 256 blocks x 1024 thr, 1 block/CU
// amdgpu_waves_per_eu(4,4): pin occupancy to exactly 4 waves/EU (1 block/CU) so the
// allocator gets the full 128-VGPR budget -> producer weights stay in registers.
__global__ __launch_bounds__(1024)
__attribute__((amdgpu_waves_per_eu(4, 4)))
void k_fused(const float* __restrict__ H0,
    const uint32_t* __restrict__ Wpack, const float* __restrict__ g_buf,
    const float* __restrict__ Wo, const float* __restrict__ bo,
    f16* __restrict__ Hn16, float* __restrict__ Y, float* __restrict__ hf_out,
    int* __restrict__ ctl){
  __shared__ __align__(16) char smem[49152];
  __shared__ int sh_role;
  __shared__ int sh_tile;
  const int tid = threadIdx.x;
  if (tid == 0) sh_role = atomicAdd(&ctl[2048], 1);
  __syncthreads();
  const int role = sh_role;

  if (role < BB){
    // ================= producer: recurrence for batch b = role =================
    const int b = role;
    uint32_t* hs16 = (uint32_t*)smem;          // Hs as f16 pairs (512 B)
    f16*      rHs16 = (f16*)(smem + 512);      // r*Hs as f16 (512 B)
    float*    hs32 = (float*)(smem + 1024);    // Hs f32 (1 KiB)
    float*    z_s  = (float*)(smem + 2048);    // z gate (1 KiB)
    const int ko = tid & 7, no = tid >> 3;

    uint32_t w[6][16];
    {
      const uint4* src = (const uint4*)(Wpack + (size_t)tid*96);
      #pragma unroll
      for (int j=0;j<24;j++){
        uint4 v = src[j];
        int f = j*4;
        w[(f+0)>>4][(f+0)&15] = v.x;
        w[(f+1)>>4][(f+1)&15] = v.y;
        w[(f+2)>>4][(f+2)&15] = v.z;
        w[(f+3)>>4][(f+3)&15] = v.w;
      }
    }

    if (tid < 256) hs32[tid] = H0[b*HH + tid];
    __syncthreads();
    if (tid < 128){
      f16x2 v; v[0] = (f16)hs32[2*tid]; v[1] = (f16)hs32[2*tid+1];
      hs16[tid] = __builtin_bit_cast(uint32_t, v);
    }
    __syncthreads();

    const int gi1 = no*4 + ko;            // used when ko<4 (in-bounds junk otherwise)
    const int gi2 = 512 + no*2 + (ko & 1);
    float g1 = g_buf[(size_t)b*768 + gi1];
    float g2 = g_buf[(size_t)b*768 + gi2];
    float g1n = 0.f, g2n = 0.f;

    for (int t = 0; t < TT; t++){
      if (t < TT-1){
        const float* gn = g_buf + (size_t)((t+1)*BB + b)*768;
        g1n = gn[gi1];
        g2n = gn[gi2];
      }

      // ---- phase 1: z (no<64) and r (no>=64) pre-activations
      uint32_t hp[16];
      {
        const uint2* hsp = (const uint2*)hs16;
        #pragma unroll
        for (int j=0;j<8;j++){ uint2 v = hsp[ko*8 + j]; hp[2*j] = v.x; hp[2*j+1] = v.y; }
      }
      float acc[4];
      #pragma unroll
      for (int ol=0;ol<4;ol++) acc[ol] = 0.f;
      #pragma unroll
      for (int p=0;p<16;p++)
        #pragma unroll
        for (int ol=0;ol<4;ol++)
          acc[ol] = dot2f(w[ol][p], hp[p], acc[ol]);
      #pragma unroll
      for (int ol=0;ol<4;ol++){
        float v2 = acc[ol];
        v2 += __shfl_xor(v2, 1);
        v2 += __shfl_xor(v2, 2);
        v2 += __shfl_xor(v2, 4);
        acc[ol] = v2;
      }
      if (ko < 4){
        float pre = acc[ko] + g1;
        float s = 1.f / (1.f + __expf(-pre));
        int o = no*4 + ko;
        if (no < 64){
          z_s[o] = s;
        } else {
          int op = o - 256;
          rHs16[op] = (f16)(s * hs32[op]);
        }
      }
      __syncthreads();

      // ---- phase 2: h~ = tanh(gh + (r*Hs)@Wh^T), Hn = z*h~ + (1-z)*Hs
      uint32_t rp[16];
      {
        const uint2* rpp = (const uint2*)rHs16;
        #pragma unroll
        for (int j=0;j<8;j++){ uint2 v = rpp[ko*8 + j]; rp[2*j] = v.x; rp[2*j+1] = v.y; }
      }
      float a2[2];
      a2[0] = 0.f; a2[1] = 0.f;
      #pragma unroll
      for (int p=0;p<16;p++)
        #pragma unroll
        for (int oi=0;oi<2;oi++)
          a2[oi] = dot2f(w[4+oi][p], rp[p], a2[oi]);
      #pragma unroll
      for (int oi=0;oi<2;oi++){
        float v2 = a2[oi];
        v2 += __shfl_xor(v2, 1);
        v2 += __shfl_xor(v2, 2);
        v2 += __shfl_xor(v2, 4);
        a2[oi] = v2;
      }
      if (ko < 2){
        int o = no*2 + ko;
        float pre = a2[ko] + g2;
        float ax = fabsf(pre);
        float e = __expf(2.f*ax);
        float th = 1.f - 2.f/(e + 1.f);      // tanh(|x|), safe at inf
        th = copysignf(th, pre);
        float z = z_s[o];
        float hn = z*th + (1.f - z)*hs32[o];
        hs32[o] = hn;
        ((f16*)hs16)[o] = (f16)hn;
        Hn16[(size_t)(t*BB + b)*HH + o] = (f16)hn;
        if (t == TT-1) hf_out[b*HH + o] = hn;
      }
      g1 = g1n; g2 = g2n;
      __syncthreads();
      // release step t: all block stores drained by the barrier; device-scope publish
      if (tid == 0){ __threadfence(); atomicAdd(&ctl[t*16], 1); }
    }
  } else {
    // ================= consumer: Y tile [m0:m0+128) x [n0:n0+256) =================
    char* a_base = smem;            // [128][64] f16, XOR-swizzled (16 KiB)
    char* b_base = smem + 16384;    // [256][64] f16, XOR-swizzled (32 KiB)
    const int lane = tid & 63, wid = tid >> 6;
    const int wm = wid & 3, wn = wid >> 2;      // 4x4 waves: 32 rows x 64 cols each
    const int arow = tid >> 3, aseg = tid & 7;  // A-staging: 128 rows x 8 seg
    const int brow = tid >> 2, bq = tid & 3;    // B-staging: 256 rows x 4 q
    int fenced_t = -1;
    for (;;){
      if (tid == 0) sh_tile = atomicAdd(&ctl[2049], 1);
      __syncthreads();
      const int tile = sh_tile;
      if (tile >= NTILE) break;
      const int mg = tile / 125;
      const int ng = tile - mg*125;
      const int m0 = mg*128, n0 = ng*256;
      const int t_need = mg*4 + 3;
      if (tid == 0 && t_need > fenced_t){
        while (atomicAdd(&ctl[t_need*16], 0) < BB) __builtin_amdgcn_s_sleep(64);
        __threadfence();           // acquire before reading Hn16
        fenced_t = t_need;
      }
      __syncthreads();

      f32x4 acc[2][4];
      {
        f32x4 z = {0.f,0.f,0.f,0.f};
        #pragma unroll
        for (int i=0;i<2;i++)
          #pragma unroll
          for (int j=0;j<4;j++) acc[i][j] = z;
      }

      #pragma unroll 1
      for (int kt=0; kt<4; kt++){
        {
          uint4 av = *(const uint4*)(Hn16 + (size_t)(m0+arow)*HH + kt*64 + aseg*8);
          *(uint4*)(a_base + ((arow*128 + aseg*16) ^ ((arow&7)<<4))) = av;
        }
        {
          const float4* bs = (const float4*)(Wo + (size_t)(n0+brow)*HH + kt*64 + bq*16);
          float4 f0=bs[0], f1=bs[1], f2=bs[2], f3=bs[3];
          f16x8 h0, h1;
          h0[0]=(f16)f0.x; h0[1]=(f16)f0.y; h0[2]=(f16)f0.z; h0[3]=(f16)f0.w;
          h0[4]=(f16)f1.x; h0[5]=(f16)f1.y; h0[6]=(f16)f1.z; h0[7]=(f16)f1.w;
          h1[0]=(f16)f2.x; h1[1]=(f16)f2.y; h1[2]=(f16)f2.z; h1[3]=(f16)f2.w;
          h1[4]=(f16)f3.x; h1[5]=(f16)f3.y; h1[6]=(f16)f3.z; h1[7]=(f16)f3.w;
          int base = brow*128 + bq*32;
          *(f16x8*)(b_base + ((base)    ^ ((brow&7)<<4))) = h0;
          *(f16x8*)(b_base + ((base+16) ^ ((brow&7)<<4))) = h1;
        }
        __syncthreads();
        #pragma unroll
        for (int kk=0; kk<2; kk++){
          const int kbyte = kk*64 + (lane>>4)*16;
          f16x8 af[2], bf[4];
          #pragma unroll
          for (int mi=0;mi<2;mi++){
            int row = wm*32 + mi*16 + (lane&15);
            af[mi] = *(const f16x8*)(a_base + ((row*128 + kbyte) ^ ((row&7)<<4)));
          }
          #pragma unroll
          for (int nj=0;nj<4;nj++){
            int rb = wn*64 + nj*16 + (lane&15);
            bf[nj] = *(const f16x8*)(b_base + ((rb*128 + kbyte) ^ ((rb&7)<<4)));
          }
          #pragma unroll
          for (int mi=0;mi<2;mi++)
            #pragma unroll
            for (int nj=0;nj<4;nj++)
              acc[mi][nj] = __builtin_amdgcn_mfma_f32_16x16x32_f16(af[mi], bf[nj], acc[mi][nj], 0, 0, 0);
        }
        __syncthreads();
      }
      // epilogue: C/D map: col = lane&15 (N), row = (lane>>4)*4 + reg (M)
      #pragma unroll
      for (int nj=0;nj<4;nj++){
        const int col = n0 + wn*64 + nj*16 + (lane & 15);
        const float bov = bo[col];
        #pragma unroll
        for (int mi=0;mi<2;mi++){
          const int rbase = m0 + wm*32 + mi*16 + (lane>>4)*4;
          #pragma unroll
          for (int r=0;r<4;r++)
            Y[(size_t)(rbase + r)*VV + col] = acc[mi][nj][r] + bov;
        }
      }
    }
  }
}

extern "C" void kernel_launch(void* const* d_in, const int* in_sizes, int n_in,
                              void* d_out, int out_size, void* d_ws, size_t ws_size,
                              hipStream_t stream){
  const int*   X  = (const int*)d_in[0];
  const float* H0 = (const float*)d_in[1];
  const float* Wz = (const float*)d_in[2];
  const float* bz = (const float*)d_in[3];
  const float* Wr = (const float*)d_in[4];
  const float* br = (const float*)d_in[5];
  const float* Wh = (const float*)d_in[6];
  const float* bh = (const float*)d_in[7];
  const float* Wo = (const float*)d_in[8];
  const float* bo = (const float*)d_in[9];
  float* out = (float*)d_out;

  char* ws = (char*)d_ws;
  float*    g_buf = (float*)ws;                               // 4096*768*4  = 12,582,912 B
  uint32_t* Wpack = (uint32_t*)(ws + 12582912);               // 1024*96*4   =    393,216 B
  f16*      Hn16  = (f16*)(ws + 12582912 + 393216);           // 4096*256*2  =  2,097,152 B
  int*      ctl   = (int*)(ws + 12582912 + 393216 + 2097152); // 2050*4      ≈      8,200 B

  k_init<<<3, 1024, 0, stream>>>(ctl);
  k_gather<<<4096, 256, 0, stream>>>(X, Wz, bz, Wr, br, Wh, bh, g_buf);
  k_pack<<<384, 256, 0, stream>>>(Wz, Wr, Wh, Wpack);
  k_fused<<<256, 1024, 0, stream>>>(H0, Wpack, g_buf, Wo, bo, Hn16, out, out + 131072000LL, ctl);
}

// Round 8
// 549.278 us; speedup vs baseline: 1.8017x; 1.7430x over previous
//
#include <hip/hip_runtime.h>
#include <hip/hip_fp16.h>
#include <stdint.h>

#define VV 32000
#define HH 256
#define BB 32
#define TT 128
#define VH 32256  // V + H

typedef _Float16 f16;
typedef _Float16 f16x2 __attribute__((ext_vector_type(2)));
typedef _Float16 f16x8 __attribute__((ext_vector_type(8)));
typedef float f32x4 __attribute__((ext_vector_type(4)));

static __device__ __forceinline__ float dot2f(uint32_t w, uint32_t h, float acc){
  f16x2 a = __builtin_bit_cast(f16x2, w);
  f16x2 b = __builtin_bit_cast(f16x2, h);
#if __has_builtin(__builtin_amdgcn_fdot2)
  return __builtin_amdgcn_fdot2(a, b, acc, false);
#else
  acc = fmaf((float)a[0], (float)b[0], acc);
  acc = fmaf((float)a[1], (float)b[1], acc);
  return acc;
#endif
}

// ---------------- gather: g[t*32+b][o] = W_gate[row][tok] + bias
__global__ void k_gather(const int* __restrict__ X,
                         const float* __restrict__ Wz, const float* __restrict__ bz,
                         const float* __restrict__ Wr, const float* __restrict__ br,
                         const float* __restrict__ Wh, const float* __restrict__ bh,
                         float* __restrict__ g_buf){
  int tb = blockIdx.x;              // t*32 + b
  int t = tb >> 5, b = tb & 31;
  int tok = X[b*TT + t];
  int o = threadIdx.x;              // 0..255
  g_buf[(size_t)tb*768 + o]       = Wz[(size_t)o*VH + tok] + bz[o];
  g_buf[(size_t)tb*768 + 256 + o] = Wr[(size_t)o*VH + tok] + br[o];
  g_buf[(size_t)tb*768 + 512 + o] = Wh[(size_t)o*VH + tok] + bh[o];
}

// ---------------- pack recurrent weights for 512-thread recurrence layout
// thread t: ko=t&7 (K-chunk [ko*32,ko*32+32)), no=t>>3 in [0,64)
// ol<8 -> o=no*8+ol (o<256: Wz row o; else Wr row o-256); ol in [8,12): Wh row no*4+(ol-8)
__global__ void k_pack(const float* __restrict__ Wz, const float* __restrict__ Wr,
                       const float* __restrict__ Wh, uint32_t* __restrict__ Wpack){
  int idx = blockIdx.x*256 + threadIdx.x;
  if (idx >= 512*192) return;
  int t = idx / 192, rem = idx - t*192;
  int ol = rem >> 4, p = rem & 15;
  int ko = t & 7, no = t >> 3;
  int k = ko*32 + p*2;
  const float* W; int row;
  if (ol < 8){ int o = no*8 + ol; if (o < 256){ W = Wz; row = o; } else { W = Wr; row = o - 256; } }
  else { W = Wh; row = no*4 + (ol - 8); }
  float a = W[(size_t)row*VH + VV + k];
  float c = W[(size_t)row*VH + VV + k + 1];
  f16x2 v; v[0] = (f16)a; v[1] = (f16)c;
  Wpack[idx] = __builtin_bit_cast(uint32_t, v);
}

// ---------------- recurrence: 32 blocks x 512 threads, waves_per_eu(2,2)
// 2 waves/SIMD max -> 256-reg budget -> 192-dword weight array truly register-resident
__global__ __launch_bounds__(512)
__attribute__((amdgpu_waves_per_eu(2, 2)))
void k_recur(const float* __restrict__ H0,
             const uint32_t* __restrict__ Wpack,
             const float* __restrict__ g_buf,
             f16* __restrict__ Hn16,
             float* __restrict__ hf_out){
  __shared__ __align__(16) uint32_t hs16[128];   // Hs as f16 pairs
  __shared__ __align__(16) f16 rHs16[256];       // r*Hs as f16
  __shared__ float hs32[256];                    // Hs f32 (state of record)
  __shared__ float z_s[256];

  const int b = blockIdx.x;
  const int tid = threadIdx.x;
  const int ko = tid & 7, no = tid >> 3;   // no in [0,64)

  // 192 packed weight dwords per thread (static indices)
  uint32_t w[12][16];
  {
    const uint4* src = (const uint4*)(Wpack + (size_t)tid*192);
    #pragma unroll
    for (int j=0;j<48;j++){
      uint4 v = src[j];
      int f = j*4;
      w[(f+0)>>4][(f+0)&15] = v.x;
      w[(f+1)>>4][(f+1)&15] = v.y;
      w[(f+2)>>4][(f+2)&15] = v.z;
      w[(f+3)>>4][(f+3)&15] = v.w;
    }
  }

  if (tid < 256) hs32[tid] = H0[b*HH + tid];
  __syncthreads();
  if (tid < 128){
    f16x2 v; v[0] = (f16)hs32[2*tid]; v[1] = (f16)hs32[2*tid+1];
    hs16[tid] = __builtin_bit_cast(uint32_t, v);
  }
  __syncthreads();

  // per-lane gate-input prefetch
  const int gi1 = no*8 + ko;                 // [0,512): this lane's phase-1 output
  const int gi2 = 512 + no*4 + (ko & 3);     // [512,768): this lane's phase-2 output
  float g1 = g_buf[(size_t)b*768 + gi1];
  float g2 = g_buf[(size_t)b*768 + gi2];
  float g1n = 0.f, g2n = 0.f;

  for (int t = 0; t < TT; t++){
    if (t < TT-1){
      const float* gn = g_buf + (size_t)((t+1)*BB + b)*768;
      g1n = gn[gi1];
      g2n = gn[gi2];
    }

    // ---- phase 1: z (no<32) and r (no>=32) pre-activations, 8 outputs per group
    uint32_t hp[16];
    {
      const uint2* hsp = (const uint2*)hs16;
      #pragma unroll
      for (int j=0;j<8;j++){ uint2 v = hsp[ko*8 + j]; hp[2*j] = v.x; hp[2*j+1] = v.y; }
    }
    float acc[8];
    #pragma unroll
    for (int ol=0;ol<8;ol++) acc[ol] = 0.f;
    #pragma unroll
    for (int p=0;p<16;p++)
      #pragma unroll
      for (int ol=0;ol<8;ol++)
        acc[ol] = dot2f(w[ol][p], hp[p], acc[ol]);
    #pragma unroll
    for (int ol=0;ol<8;ol++){
      float v2 = acc[ol];
      v2 += __shfl_xor(v2, 1);
      v2 += __shfl_xor(v2, 2);
      v2 += __shfl_xor(v2, 4);
      acc[ol] = v2;
    }
    // lane ko takes output ol=ko (select chain, no dynamic register indexing)
    {
      float sel = acc[0];
      #pragma unroll
      for (int ol=1;ol<8;ol++) sel = (ko == ol) ? acc[ol] : sel;
      float pre = sel + g1;
      float s = 1.f / (1.f + __expf(-pre));
      int o = no*8 + ko;
      if (no < 32){
        z_s[o] = s;
      } else {
        int op = o - 256;
        rHs16[op] = (f16)(s * hs32[op]);
      }
    }
    __syncthreads();

    // ---- phase 2: h~ = tanh(gh + (r*Hs)@Wh^T), Hn = z*h~ + (1-z)*Hs
    uint32_t rp[16];
    {
      const uint2* rpp = (const uint2*)rHs16;
      #pragma unroll
      for (int j=0;j<8;j++){ uint2 v = rpp[ko*8 + j]; rp[2*j] = v.x; rp[2*j+1] = v.y; }
    }
    float a2[4];
    #pragma unroll
    for (int oi=0;oi<4;oi++) a2[oi] = 0.f;
    #pragma unroll
    for (int p=0;p<16;p++)
      #pragma unroll
      for (int oi=0;oi<4;oi++)
        a2[oi] = dot2f(w[8+oi][p], rp[p], a2[oi]);
    #pragma unroll
    for (int oi=0;oi<4;oi++){
      float v2 = a2[oi];
      v2 += __shfl_xor(v2, 1);
      v2 += __shfl_xor(v2, 2);
      v2 += __shfl_xor(v2, 4);
      a2[oi] = v2;
    }
    if (ko < 4){
      float sel = a2[0];
      #pragma unroll
      for (int oi=1;oi<4;oi++) sel = (ko == oi) ? a2[oi] : sel;
      int o = no*4 + ko;
      float pre = sel + g2;
      float ax = fabsf(pre);
      float e = __expf(2.f*ax);
      float th = 1.f - 2.f/(e + 1.f);      // tanh(|x|), safe at inf
      th = copysignf(th, pre);
      float z = z_s[o];
      float hn = z*th + (1.f - z)*hs32[o];
      hs32[o] = hn;
      ((f16*)hs16)[o] = (f16)hn;
      Hn16[(size_t)(t*BB + b)*HH + o] = (f16)hn;
      if (t == TT-1) hf_out[b*HH + o] = hn;
    }
    g1 = g1n; g2 = g2n;
    __syncthreads();
  }
}

// ---------------- output GEMM: Y[4096][32000] = Hn16[4096][256] @ Wo^T (f16 MFMA) + bo
__global__ __launch_bounds__(256) void k_gemm(const f16* __restrict__ A, const float* __restrict__ Wo,
                                              const float* __restrict__ bo, float* __restrict__ Y){
  __shared__ __align__(16) f16 a_lds[128*128];
  __shared__ __align__(16) f16 b_lds[128*128];
  const int m0 = blockIdx.x * 128;   // m fastest -> consecutive blocks share Wo n-panel in L2
  const int n0 = blockIdx.y * 128;
  const int tid = threadIdx.x;
  const int lane = tid & 63, wave = tid >> 6;
  const int wm = wave >> 1, wn = wave & 1;

  f32x4 acc[4][4];
  {
    f32x4 z = {0.f, 0.f, 0.f, 0.f};
    #pragma unroll
    for (int i=0;i<4;i++)
      #pragma unroll
      for (int j=0;j<4;j++) acc[i][j] = z;
  }

  const int srow = tid >> 1, seg = tid & 1;
  #pragma unroll 1
  for (int kt=0; kt<2; kt++){
    const int k0 = kt*128;
    {
      const uint4* asrc = (const uint4*)(A + (size_t)(m0+srow)*256 + k0 + seg*64);
      #pragma unroll
      for (int j=0;j<8;j++){
        uint4 v = asrc[j];
        int byte = (srow*256 + seg*128 + j*16) ^ ((srow&7)<<4);
        *(uint4*)((char*)a_lds + byte) = v;
      }
      const float4* bsrc = (const float4*)(Wo + (size_t)(n0+srow)*256 + k0 + seg*64);
      #pragma unroll
      for (int j=0;j<8;j++){
        float4 f0 = bsrc[2*j], f1 = bsrc[2*j+1];
        f16x8 hv;
        hv[0]=(f16)f0.x; hv[1]=(f16)f0.y; hv[2]=(f16)f0.z; hv[3]=(f16)f0.w;
        hv[4]=(f16)f1.x; hv[5]=(f16)f1.y; hv[6]=(f16)f1.z; hv[7]=(f16)f1.w;
        int byte = (srow*256 + seg*128 + j*16) ^ ((srow&7)<<4);
        *(f16x8*)((char*)b_lds + byte) = hv;
      }
    }
    __syncthreads();
    #pragma unroll
    for (int kk=0; kk<4; kk++){
      const int kbyte = kk*64 + (lane>>4)*16;
      f16x8 af[4], bf[4];
      #pragma unroll
      for (int mi=0;mi<4;mi++){
        int row = wm*64 + mi*16 + (lane&15);
        int byte = (row*256 + kbyte) ^ ((row&7)<<4);
        af[mi] = *(const f16x8*)((const char*)a_lds + byte);
      }
      #pragma unroll
      for (int nj=0;nj<4;nj++){
        int nl = wn*64 + nj*16 + (lane&15);
        int byte = (nl*256 + kbyte) ^ ((nl&7)<<4);
        bf[nj] = *(const f16x8*)((const char*)b_lds + byte);
      }
      #pragma unroll
      for (int mi=0;mi<4;mi++)
        #pragma unroll
        for (int nj=0;nj<4;nj++)
          acc[mi][nj] = __builtin_amdgcn_mfma_f32_16x16x32_f16(af[mi], bf[nj], acc[mi][nj], 0, 0, 0);
    }
    __syncthreads();
  }
  // epilogue: C/D map: col = lane&15, row = (lane>>4)*4 + reg
  #pragma unroll
  for (int nj=0;nj<4;nj++){
    const int col = n0 + wn*64 + nj*16 + (lane & 15);
    const float bov = bo[col];
    #pragma unroll
    for (int mi=0;mi<4;mi++){
      const int rbase = m0 + wm*64 + mi*16 + (lane>>4)*4;
      #pragma unroll
      for (int r=0;r<4;r++){
        Y[(size_t)(rbase + r)*VV + col] = acc[mi][nj][r] + bov;
      }
    }
  }
}

extern "C" void kernel_launch(void* const* d_in, const int* in_sizes, int n_in,
                              void* d_out, int out_size, void* d_ws, size_t ws_size,
                              hipStream_t stream){
  const int*   X  = (const int*)d_in[0];
  const float* H0 = (const float*)d_in[1];
  const float* Wz = (const float*)d_in[2];
  const float* bz = (const float*)d_in[3];
  const float* Wr = (const float*)d_in[4];
  const float* br = (const float*)d_in[5];
  const float* Wh = (const float*)d_in[6];
  const float* bh = (const float*)d_in[7];
  const float* Wo = (const float*)d_in[8];
  const float* bo = (const float*)d_in[9];
  float* out = (float*)d_out;

  char* ws = (char*)d_ws;
  float*    g_buf = (float*)ws;                               // 4096*768*4  = 12,582,912 B
  uint32_t* Wpack = (uint32_t*)(ws + 12582912);               // 512*192*4   =    393,216 B
  f16*      Hn16  = (f16*)(ws + 12582912 + 393216);           // 4096*256*2  =  2,097,152 B

  k_gather<<<4096, 256, 0, stream>>>(X, Wz, bz, Wr, br, Wh, bh, g_buf);
  k_pack<<<384, 256, 0, stream>>>(Wz, Wr, Wh, Wpack);
  k_recur<<<32, 512, 0, stream>>>(H0, Wpack, g_buf, Hn16, out + 131072000LL);
  k_gemm<<<dim3(32, 250), 256, 0, stream>>>(Hn16, Wo, bo, out);
}